// Round 8
// baseline (136.183 us; speedup 1.0000x reference)
//
#include <hip/hip_runtime.h>
#include <hip/hip_bf16.h>
#include <stdint.h>

// MHA: B=2, S=2048, D=1024, H=16, dk=64.  All GEMM-shaped work in bf16 MFMA.
// conv->bf16 | QKV gemm (LOG2E/8 folded into Wq,bq; V written transposed
// [bh][d][s]) | flash attn 32x32x16 MFMA, in-register P (cvt_pk+permlane),
// no-max softmax, KEY-SPLIT x2: 8-wave blocks, 2 key-groups x 4 waves, each
// group owns half the keys + its own K/V double buffer; additive combine at
// the end (no-max softmax => no rescale needed) | O-proj gemm -> f32.

#define LOG2E 1.4426950408889634f

typedef float f32x4 __attribute__((ext_vector_type(4)));
typedef float f32x16 __attribute__((ext_vector_type(16)));
typedef short bf16x8 __attribute__((ext_vector_type(8)));
typedef short bf16x4 __attribute__((ext_vector_type(4)));
typedef unsigned int u32x2 __attribute__((ext_vector_type(2)));

__device__ __forceinline__ unsigned short f2bf(float f) {
  __hip_bfloat16 h = __float2bfloat16(f);
  return reinterpret_cast<unsigned short&>(h);
}

#define GLDS(g, l) __builtin_amdgcn_global_load_lds(                          \
    (const __attribute__((address_space(1))) void*)(g),                       \
    (__attribute__((address_space(3))) void*)(l), 16, 0, 0)

// ---------- fp32 -> bf16 conversion ----------
__global__ __launch_bounds__(256) void k_conv(const float* __restrict__ src,
                                              unsigned short* __restrict__ dst,
                                              int n4, float scale) {
  int i = blockIdx.x * 256 + threadIdx.x;
  const int stride = gridDim.x * 256;
  for (; i < n4; i += stride) {
    float4 v = ((const float4*)src)[i];
    ushort4 o;
    o.x = f2bf(v.x * scale);
    o.y = f2bf(v.y * scale);
    o.z = f2bf(v.z * scale);
    o.w = f2bf(v.w * scale);
    ((ushort4*)dst)[i] = o;
  }
}

// all 4 weight matrices in one launch; Wq scaled by LOG2E/8
__global__ __launch_bounds__(256) void k_convW(const float* __restrict__ wq,
                                               const float* __restrict__ wk,
                                               const float* __restrict__ wv,
                                               const float* __restrict__ wo,
                                               unsigned short* __restrict__ dq,
                                               unsigned short* __restrict__ dk,
                                               unsigned short* __restrict__ dv,
                                               unsigned short* __restrict__ dw) {
  const int m = blockIdx.y;
  const float* src = (m == 0) ? wq : (m == 1) ? wk : (m == 2) ? wv : wo;
  unsigned short* dst = (m == 0) ? dq : (m == 1) ? dk : (m == 2) ? dv : dw;
  const float scale = (m == 0) ? (0.125f * LOG2E) : 1.0f;
  int i = blockIdx.x * 256 + threadIdx.x;
  float4 v = ((const float4*)src)[i];
  ushort4 o;
  o.x = f2bf(v.x * scale);
  o.y = f2bf(v.y * scale);
  o.z = f2bf(v.z * scale);
  o.w = f2bf(v.w * scale);
  ((ushort4*)dst)[i] = o;
}

// fused bias vector [3072]: bq*LOG2E/8 | bk | bv
__global__ __launch_bounds__(256) void k_bias(const float* __restrict__ bq,
                                              const float* __restrict__ bk,
                                              const float* __restrict__ bv,
                                              float* __restrict__ out) {
  int i = blockIdx.x * 256 + threadIdx.x;
  float v;
  if (i < 1024) v = bq[i] * (0.125f * LOG2E);
  else if (i < 2048) v = bk[i - 1024];
  else v = bv[i - 2048];
  out[i] = v;
}

// ---------- GEMM: C[m][n] = sum_k A[m][k]*B[n][k] + bias[n] ----------
template <int MODE>
__global__ __launch_bounds__(256) void k_gemm(const unsigned short* __restrict__ A,
                                              const unsigned short* __restrict__ B,
                                              const float* __restrict__ bias,
                                              void* __restrict__ outp) {
  __shared__ unsigned short As[128 * 32];
  __shared__ unsigned short Bs[128 * 32];
  const int tid = threadIdx.x;
  const int lane = tid & 63, wid = tid >> 6;
  const int wr = wid >> 1, wc = wid & 1;
  const int r = lane & 15, g = lane >> 4;
  const int bm = blockIdx.x, bn = blockIdx.y;

  const unsigned short* gA = A + (size_t)bm * 128 * 1024;
  const unsigned short* gB = B + (size_t)bn * 128 * 1024;
  const int row0 = tid >> 2, cg = (tid & 3) * 8;

  f32x4 acc[4][4] = {};

  for (int k0 = 0; k0 < 1024; k0 += 32) {
    __syncthreads();
    GLDS(gA + (size_t)row0 * 1024 + k0 + cg,        As + row0 * 32 + cg);
    GLDS(gA + (size_t)(row0 + 64) * 1024 + k0 + cg, As + (row0 + 64) * 32 + cg);
    GLDS(gB + (size_t)row0 * 1024 + k0 + cg,        Bs + row0 * 32 + cg);
    GLDS(gB + (size_t)(row0 + 64) * 1024 + k0 + cg, Bs + (row0 + 64) * 32 + cg);
    __syncthreads();

    bf16x8 af[4], bfr[4];
#pragma unroll
    for (int i = 0; i < 4; i++) {
      af[i]  = *(const bf16x8*)(As + (wr * 64 + i * 16 + r) * 32 + g * 8);
      bfr[i] = *(const bf16x8*)(Bs + (wc * 64 + i * 16 + r) * 32 + g * 8);
    }
#pragma unroll
    for (int i = 0; i < 4; i++)
#pragma unroll
      for (int j = 0; j < 4; j++)
        acc[i][j] = __builtin_amdgcn_mfma_f32_16x16x32_bf16(af[i], bfr[j], acc[i][j], 0, 0, 0);
  }

#pragma unroll
  for (int i = 0; i < 4; i++) {
    const int rowb = bm * 128 + wr * 64 + i * 16 + g * 4;
#pragma unroll
    for (int j = 0; j < 4; j++) {
      const int col = bn * 128 + wc * 64 + j * 16 + r;
      const float bv = bias[col];
#pragma unroll
      for (int t = 0; t < 4; t++) {
        const int row = rowb + t;
        const float val = acc[i][j][t] + bv;
        if (MODE == 0) {
          const int mat = col >> 10, nn = col & 1023;
          const int hh = nn >> 6, dd = nn & 63;
          const int bb = row >> 11, ss = row & 2047;
          size_t idx;
          if (mat == 2)  // V transposed: [bh][d][s]
            idx = (size_t)2 * 4194304 + (size_t)((bb * 16 + hh) * 64 + dd) * 2048 + ss;
          else
            idx = (size_t)mat * 4194304 + (size_t)((bb * 16 + hh) * 2048 + ss) * 64 + dd;
          ((unsigned short*)outp)[idx] = f2bf(val);
        } else {
          ((float*)outp)[(size_t)row * 1024 + col] = val;
        }
      }
    }
  }
}

// ---------- flash attention (32x32 MFMA, key-split x2, in-register P) ------
// grid (16 q-tiles of 128, 32 b*h), 512 threads = 2 key-groups x 4 waves.
// Wave w of group kg owns q-rows q0 + w*32 + (lane&31), keys kg*1024..+1023
// (16 tiles of 64).  Each group: own K/V double buffer, fragment-order
// global_load_lds staging.  No-max softmax => final combine is o+=o', l+=l'.
// Per 32-key subtile: 4 QK MFMA -> 16 exp2 -> 8 cvt_pk + 4 permlane32_swap
// (in-register P B-frags) -> 4 PV MFMA.  All compile-time indexing.
__global__ __launch_bounds__(512, 4) void k_attn(const unsigned short* __restrict__ Q,
                                                 const unsigned short* __restrict__ Km,
                                                 const unsigned short* __restrict__ Vt,
                                                 unsigned short* __restrict__ merged) {
  __shared__ unsigned short Kb[2][2][4096];   // [group][buf] 32 KB
  __shared__ unsigned short Vb[2][2][4096];   // 32 KB
  const int tid = threadIdx.x;
  const int kg = tid >> 8, gtid = tid & 255;
  const int lane = tid & 63, w = (tid >> 6) & 3;
  const int l31 = lane & 31, hi = lane >> 5;
  const int bh = blockIdx.y;
  const int b = bh >> 4, h = bh & 15;
  const int q0 = blockIdx.x * 128;

  const unsigned short* Qh  = Q  + (size_t)bh * 131072;              // [s][d]
  const unsigned short* KhG = Km + (size_t)bh * 131072 + (size_t)kg * 65536;  // [s][d]
  const unsigned short* VtG = Vt + (size_t)bh * 131072 + 1024 * kg;  // [d][s]

  const int qrow = q0 + w * 32 + l31;
  bf16x8 bQ[4];
#pragma unroll
  for (int c = 0; c < 4; c++)
    bQ[c] = *(const bf16x8*)(Qh + (size_t)qrow * 64 + c * 16 + hi * 8);

  // staging source perms (chunk id = op*256+gtid -> (s, c, l2))
  int ksrc[2], vsrc[2];
#pragma unroll
  for (int op = 0; op < 2; op++) {
    const int ck = op * 256 + gtid;
    const int s = ck >> 8, c = (ck >> 6) & 3, l2 = ck & 63;
    ksrc[op] = (s * 32 + (l2 & 31)) * 64 + c * 16 + (l2 >> 5) * 8;
    vsrc[op] = (s * 32 + (l2 & 31)) * 2048 + c * 16 + (l2 >> 5) * 8;
  }
  const int ldst = gtid * 8;

  GLDS(KhG + ksrc[0], &Kb[kg][0][ldst]);
  GLDS(KhG + ksrc[1], &Kb[kg][0][2048 + ldst]);
  GLDS(VtG + vsrc[0], &Vb[kg][0][ldst]);
  GLDS(VtG + vsrc[1], &Vb[kg][0][2048 + ldst]);
  __syncthreads();

  f32x16 o0 = {0.f,0.f,0.f,0.f,0.f,0.f,0.f,0.f,0.f,0.f,0.f,0.f,0.f,0.f,0.f,0.f};
  f32x16 o1 = o0;
  float lsum = 0.f;

  for (int t = 0; t < 16; ++t) {
    const int cur = t & 1;
    if (t < 15) {
      const size_t kv = (size_t)(t + 1) * 64;
      GLDS(KhG + kv * 64 + ksrc[0], &Kb[kg][cur ^ 1][ldst]);
      GLDS(KhG + kv * 64 + ksrc[1], &Kb[kg][cur ^ 1][2048 + ldst]);
      GLDS(VtG + kv + vsrc[0], &Vb[kg][cur ^ 1][ldst]);
      GLDS(VtG + kv + vsrc[1], &Vb[kg][cur ^ 1][2048 + ldst]);
    }

    const unsigned short* kb = &Kb[kg][cur][0];
    const unsigned short* vb = &Vb[kg][cur][0];

    // one 32-key subtile: QK -> exp2 -> in-reg P frags -> PV.
    // All indices compile-time (SC literal 0/1) to keep p[] in registers.
#define SUBTILE(SC)                                                            \
    {                                                                          \
      bf16x8 kf0 = *(const bf16x8*)(kb + (((SC)*4 + 0) * 64 + lane) * 8);      \
      bf16x8 kf1 = *(const bf16x8*)(kb + (((SC)*4 + 1) * 64 + lane) * 8);      \
      bf16x8 kf2 = *(const bf16x8*)(kb + (((SC)*4 + 2) * 64 + lane) * 8);      \
      bf16x8 kf3 = *(const bf16x8*)(kb + (((SC)*4 + 3) * 64 + lane) * 8);      \
      f32x16 St = {0.f,0.f,0.f,0.f,0.f,0.f,0.f,0.f,                            \
                   0.f,0.f,0.f,0.f,0.f,0.f,0.f,0.f};                           \
      St = __builtin_amdgcn_mfma_f32_32x32x16_bf16(kf0, bQ[0], St, 0, 0, 0);   \
      St = __builtin_amdgcn_mfma_f32_32x32x16_bf16(kf1, bQ[1], St, 0, 0, 0);   \
      St = __builtin_amdgcn_mfma_f32_32x32x16_bf16(kf2, bQ[2], St, 0, 0, 0);   \
      St = __builtin_amdgcn_mfma_f32_32x32x16_bf16(kf3, bQ[3], St, 0, 0, 0);   \
      float p[16];                                                             \
      float ps = 0.f;                                                          \
      _Pragma("unroll")                                                        \
      for (int u = 0; u < 16; u++) {                                           \
        p[u] = __builtin_amdgcn_exp2f(St[u]);                                  \
        ps += p[u];                                                            \
      }                                                                        \
      lsum += ps;                                                              \
      unsigned int a0, a1, b0, b1;                                             \
      asm("v_cvt_pk_bf16_f32 %0, %1, %2" : "=v"(a0) : "v"(p[0]), "v"(p[1]));   \
      asm("v_cvt_pk_bf16_f32 %0, %1, %2" : "=v"(a1) : "v"(p[2]), "v"(p[3]));   \
      asm("v_cvt_pk_bf16_f32 %0, %1, %2" : "=v"(b0) : "v"(p[4]), "v"(p[5]));   \
      asm("v_cvt_pk_bf16_f32 %0, %1, %2" : "=v"(b1) : "v"(p[6]), "v"(p[7]));   \
      u32x2 r0 = __builtin_amdgcn_permlane32_swap(a0, b0, false, false);       \
      u32x2 r1 = __builtin_amdgcn_permlane32_swap(a1, b1, false, false);       \
      union { unsigned int u[4]; bf16x8 v; } pfE;                              \
      pfE.u[0] = r0[0]; pfE.u[1] = r1[0]; pfE.u[2] = r0[1]; pfE.u[3] = r1[1];  \
      asm("v_cvt_pk_bf16_f32 %0, %1, %2" : "=v"(a0) : "v"(p[8]), "v"(p[9]));   \
      asm("v_cvt_pk_bf16_f32 %0, %1, %2" : "=v"(a1) : "v"(p[10]), "v"(p[11])); \
      asm("v_cvt_pk_bf16_f32 %0, %1, %2" : "=v"(b0) : "v"(p[12]), "v"(p[13])); \
      asm("v_cvt_pk_bf16_f32 %0, %1, %2" : "=v"(b1) : "v"(p[14]), "v"(p[15])); \
      r0 = __builtin_amdgcn_permlane32_swap(a0, b0, false, false);             \
      r1 = __builtin_amdgcn_permlane32_swap(a1, b1, false, false);             \
      union { unsigned int u[4]; bf16x8 v; } pfO;                              \
      pfO.u[0] = r0[0]; pfO.u[1] = r1[0]; pfO.u[2] = r0[1]; pfO.u[3] = r1[1];  \
      bf16x8 v00 = *(const bf16x8*)(vb + ((0 + 2*(SC)) * 64 + lane) * 8);      \
      bf16x8 v01 = *(const bf16x8*)(vb + ((1 + 2*(SC)) * 64 + lane) * 8);      \
      bf16x8 v10 = *(const bf16x8*)(vb + ((4 + 2*(SC)) * 64 + lane) * 8);      \
      bf16x8 v11 = *(const bf16x8*)(vb + ((5 + 2*(SC)) * 64 + lane) * 8);      \
      o0 = __builtin_amdgcn_mfma_f32_32x32x16_bf16(v00, pfE.v, o0, 0, 0, 0);   \
      o0 = __builtin_amdgcn_mfma_f32_32x32x16_bf16(v01, pfO.v, o0, 0, 0, 0);   \
      o1 = __builtin_amdgcn_mfma_f32_32x32x16_bf16(v10, pfE.v, o1, 0, 0, 0);   \
      o1 = __builtin_amdgcn_mfma_f32_32x32x16_bf16(v11, pfO.v, o1, 0, 0, 0);   \
    }

    SUBTILE(0)
    SUBTILE(1)
#undef SUBTILE

    __syncthreads();   // drains stage vmcnt + protects buffer reuse
  }

  // ---- key-group combine: group 1 -> LDS (swizzled), group 0 adds ----
  float* lbuf = (float*)&Vb[0][0][0];
  char*  ob   = (char*)&Kb[0][0][0] + gtid * 128;
  const unsigned sw2 = ((unsigned)(gtid & 7)) << 4;
  if (kg == 1) {
#pragma unroll
    for (int j = 0; j < 4; j++) {
      float4 t0 = { o0[4*j], o0[4*j+1], o0[4*j+2], o0[4*j+3] };
      *(float4*)(ob + (((unsigned)(j * 16)) ^ sw2)) = t0;
    }
#pragma unroll
    for (int j = 0; j < 4; j++) {
      float4 t1 = { o1[4*j], o1[4*j+1], o1[4*j+2], o1[4*j+3] };
      *(float4*)(ob + (((unsigned)(64 + j * 16)) ^ sw2)) = t1;
    }
    lbuf[gtid] = lsum;
  }
  __syncthreads();
  if (kg == 0) {
#pragma unroll
    for (int j = 0; j < 4; j++) {
      float4 t0 = *(const float4*)(ob + (((unsigned)(j * 16)) ^ sw2));
      o0[4*j] += t0.x; o0[4*j+1] += t0.y; o0[4*j+2] += t0.z; o0[4*j+3] += t0.w;
    }
#pragma unroll
    for (int j = 0; j < 4; j++) {
      float4 t1 = *(const float4*)(ob + (((unsigned)(64 + j * 16)) ^ sw2));
      o1[4*j] += t1.x; o1[4*j+1] += t1.y; o1[4*j+2] += t1.z; o1[4*j+3] += t1.w;
    }
    lsum += lbuf[gtid];

    // epilogue: o[ds] reg t -> d = ds*32 + (t&3) + 8*(t>>2) + 4*hi; q = lane&31
    const float inv = 1.0f / (lsum + __shfl_xor(lsum, 32));
    const size_t base = (size_t)(b * 2048 + qrow) * 1024 + h * 64;
#pragma unroll
    for (int ds = 0; ds < 2; ds++) {
      const f32x16& oo = ds ? o1 : o0;
#pragma unroll
      for (int m = 0; m < 4; m++) {
        bf16x4 ov;
#pragma unroll
        for (int i = 0; i < 4; i++) ov[i] = (short)f2bf(oo[m * 4 + i] * inv);
        *(bf16x4*)(&merged[base + ds * 32 + m * 8 + hi * 4]) = ov;
      }
    }
  }
}

extern "C" void kernel_launch(void* const* d_in, const int* in_sizes, int n_in,
                              void* d_out, int out_size, void* d_ws, size_t ws_size,
                              hipStream_t stream) {
  const float* x  = (const float*)d_in[0];
  const float* Wq = (const float*)d_in[1];
  const float* bq = (const float*)d_in[2];
  const float* Wk = (const float*)d_in[3];
  const float* bk = (const float*)d_in[4];
  const float* Wv = (const float*)d_in[5];
  const float* bv = (const float*)d_in[6];
  const float* Wo = (const float*)d_in[7];
  const float* bo = (const float*)d_in[8];

  if (ws_size < (size_t)50343936) return;   // need ~48 MB

  unsigned short* ws  = (unsigned short*)d_ws;
  unsigned short* xb  = ws;               // x bf16           [4096][1024]
  unsigned short* Wb  = ws + 4194304;     // Wq'|Wk|Wv bf16   [3072][1024]
  unsigned short* Wob = ws + 7340032;     // Wo bf16          [1024][1024]
  unsigned short* qkv = ws + 8388608;     // Q|K bf16 [32][2048][64]; Vt [32][64][2048]
  unsigned short* mrg = ws + 20971520;    // merged bf16      [4096][1024]
  float* biasQ = (float*)(ws + 25165824); // fused qkv bias   [3072] f32

  k_conv<<<dim3(2048), dim3(256), 0, stream>>>(x, xb, 1048576, 1.0f);
  k_convW<<<dim3(1024, 4), dim3(256), 0, stream>>>(Wq, Wk, Wv, Wo,
      Wb, Wb + 1048576, Wb + 2097152, Wob);
  k_bias<<<dim3(12), dim3(256), 0, stream>>>(bq, bk, bv, biasQ);

  k_gemm<0><<<dim3(32, 24), dim3(256), 0, stream>>>(xb, Wb, biasQ, (void*)qkv);
  k_attn<<<dim3(16, 32), dim3(512), 0, stream>>>(qkv, qkv + 4194304, qkv + 8388608, mrg);
  k_gemm<1><<<dim3(32, 8), dim3(256), 0, stream>>>(mrg, Wob, bo, d_out);
}